// Round 6
// baseline (243.783 us; speedup 1.0000x reference)
//
#include <hip/hip_runtime.h>

typedef _Float16 H16;
typedef _Float16 half8 __attribute__((ext_vector_type(8)));
typedef _Float16 half4 __attribute__((ext_vector_type(4)));
typedef float f32x4 __attribute__((ext_vector_type(4)));

// problem dims
constexpr int Bb = 2, S = 2048, D = 1024, NH = 16, HW = 64;
constexpr int M = Bb * S;  // 4096

// workspace layout (bytes) — identical to the proven 166us version (38 MB)
constexpr size_t XH_OFF = 0;                               // [M][D] f16
constexpr size_t WT_OFF = XH_OFF + (size_t)M * D * 2;      // 3x [D(n)][D(k)] f16
constexpr size_t Q_OFF  = WT_OFF + 3ull * D * D * 2;       // [B][NH][S][HW] f16
constexpr size_t K_OFF  = Q_OFF + (size_t)M * D * 2;       // [B][NH][S][HW] f16
constexpr size_t VT_OFF = K_OFF + (size_t)M * D * 2;       // [B][NH][HW][S] f16

#define GLOAD_LDS16(g, l)                                        \
  __builtin_amdgcn_global_load_lds(                              \
      (const __attribute__((address_space(1))) void*)(g),        \
      (__attribute__((address_space(3))) void*)(l), 16, 0, 0)

// ---------------- fused prep: x fp32->fp16 (z=0) + W^T fp16 (z=1..3) --------
__global__ __launch_bounds__(256) void prep(const float* __restrict__ x,
                                            H16* __restrict__ xh,
                                            const float* __restrict__ w0,
                                            const float* __restrict__ w1,
                                            const float* __restrict__ w2,
                                            H16* __restrict__ wt) {
  __shared__ H16 tile[64][65];
  const int z = blockIdx.z;
  const int t = threadIdx.x;
  if (z == 0) {
    // 256 blocks, each converts 8 chunks of 2048 f16
    const int bid = blockIdx.y * 16 + blockIdx.x;
#pragma unroll
    for (int r = 0; r < 8; ++r) {
      size_t i = ((size_t)(bid * 8 + r) * 256 + t) * 8;
      float4 a = *(const float4*)(x + i);
      float4 b = *(const float4*)(x + i + 4);
      half8 h = {(H16)a.x, (H16)a.y, (H16)a.z, (H16)a.w,
                 (H16)b.x, (H16)b.y, (H16)b.z, (H16)b.w};
      *(half8*)(xh + i) = h;
    }
  } else {
    const float* w = z == 1 ? w0 : z == 2 ? w1 : w2;
    H16* out = wt + (size_t)(z - 1) * D * D;
    int c = t & 63, r4 = t >> 6;
    int bx = blockIdx.x * 64, by = blockIdx.y * 64;
#pragma unroll 4
    for (int it = 0; it < 16; ++it) {
      int row = it * 4 + r4;
      tile[c][row] = (H16)w[(size_t)(by + row) * D + bx + c];
    }
    __syncthreads();
#pragma unroll 4
    for (int it = 0; it < 16; ++it) {
      int row = it * 4 + r4;
      out[(size_t)(bx + row) * D + by + c] = tile[row][c];
    }
  }
}

// ---------------- fused QKV GEMM (fp16 MFMA, 128x128x64, swizzled) ----------
// Round-4 measured version (48.2 us, 0 bank conflicts, FETCH 29.8MB):
// T2 XOR swizzle via pre-swizzled global source + XCD-aware remap.
// (Round-5 dbuf experiment was neutral-to-negative -> reverted.)
__global__ __launch_bounds__(256) void qkv_gemm(
    const H16* __restrict__ xh, const H16* __restrict__ wt,
    const float* __restrict__ bq, const float* __restrict__ bk,
    const float* __restrict__ bv, H16* __restrict__ qo, H16* __restrict__ ko,
    H16* __restrict__ vto) {
  __shared__ __align__(16) H16 As[128 * 64];
  __shared__ __align__(16) H16 Bs[128 * 64];
  const int lin = blockIdx.x + blockIdx.y * 8 + blockIdx.z * 256;
  const int wid = (lin & 7) * 96 + (lin >> 3);
  const int z = wid >> 8;
  const int rem = wid & 255;
  const int bm = (rem >> 3) * 128, bn = (rem & 7) * 128;
  const H16* w = wt + (size_t)z * D * D;
  const float* bias = z == 0 ? bq : z == 1 ? bk : bv;
  const int t = threadIdx.x;
  const int wave = t >> 6, lane = t & 63;
  const int g = lane >> 4, c = lane & 15;
  const int wm = (wave >> 1) * 64, wn = (wave & 1) * 64;

  // swizzled fragment read offsets (row&7 == c&7 since wm,i*16 are 16-mult)
  const int sw0 = (g ^ (c & 7)) * 8;
  const int sw1 = ((4 + g) ^ (c & 7)) * 8;

  f32x4 acc[4][4] = {};

  for (int kk = 0; kk < D; kk += 64) {
#pragma unroll
    for (int rnd = 0; rnd < 4; ++rnd) {
      int cid = rnd * 256 + t;
      int row = cid >> 3, j = cid & 7;
      int k0 = (j ^ (row & 7)) * 8;  // pre-swizzled global source
      GLOAD_LDS16(&xh[(size_t)(bm + row) * D + kk + k0], &As[cid * 8]);
      GLOAD_LDS16(&w[(size_t)(bn + row) * D + kk + k0], &Bs[cid * 8]);
    }
    __syncthreads();
#pragma unroll
    for (int kc = 0; kc < 2; ++kc) {
      const int ro = kc ? sw1 : sw0;
      half8 af[4], bf[4];
#pragma unroll
      for (int i = 0; i < 4; ++i) {
        af[i] = *(const half8*)&As[(wm + i * 16 + c) * 64 + ro];
        bf[i] = *(const half8*)&Bs[(wn + i * 16 + c) * 64 + ro];
      }
#pragma unroll
      for (int i = 0; i < 4; ++i)
#pragma unroll
        for (int j2 = 0; j2 < 4; ++j2)
          acc[i][j2] = __builtin_amdgcn_mfma_f32_16x16x32_f16(af[i], bf[j2],
                                                              acc[i][j2], 0, 0, 0);
    }
    __syncthreads();
  }

#pragma unroll
  for (int i = 0; i < 4; ++i) {
#pragma unroll
    for (int j = 0; j < 4; ++j) {
      int coln = bn + wn + j * 16 + c;
      float bse = bias[coln];
      int h = coln >> 6, wcol = coln & 63;
      if (z == 2) {
        int row0 = bm + wm + i * 16 + g * 4;
        int bbx = row0 >> 11, s0 = row0 & (S - 1);
        half4 v4 = {(H16)(acc[i][j][0] + bse), (H16)(acc[i][j][1] + bse),
                    (H16)(acc[i][j][2] + bse), (H16)(acc[i][j][3] + bse)};
        *(half4*)&vto[((size_t)(bbx * NH + h) * HW + wcol) * S + s0] = v4;
      } else {
#pragma unroll
        for (int r = 0; r < 4; ++r) {
          int row = bm + wm + i * 16 + g * 4 + r;
          float val = acc[i][j][r] + bse;
          int bbx = row >> 11, s = row & (S - 1);
          size_t bh = (size_t)(bbx * NH + h);
          if (z == 0)
            qo[(bh * S + s) * HW + wcol] = (H16)val;
          else
            ko[(bh * S + s) * HW + wcol] = (H16)val;
        }
      }
    }
  }
}

// ---------------- flash attention v14: no-LDS, barrier-free main loop ------
// K/V working set is L2-resident (4 heads/XCD x 512KB = 2MB < 4MB L2 — the
// point of the bh swizzle), so LDS staging was pure overhead (guide common-
// mistake #7). K and V fragments now load DIRECTLY from global with per-lane
// addresses; the kperm permutation that keeps P register-resident moves into
// the K address (free). No staging, no DMA, no barriers in the loop: waves
// free-run (max phase diversity / latency overlap). Numerics: identical
// fragments and MFMA order as v13 (passed).
// LDS only for the kg-combine epilogue (32KB+). 2 blocks/CU, 16 waves/CU.
__global__ __launch_bounds__(512, 4) void attn(const H16* __restrict__ q,
                                               const H16* __restrict__ k,
                                               const H16* __restrict__ vt,
                                               float* __restrict__ out) {
  constexpr int NIT = S / 128;  // 16 chunks of 64 keys per key-group
  __shared__ float pex[4][2048];  // combine exchange, 32KB
  __shared__ float lx[4][2][16];

  const int id = blockIdx.x;  // 512 blocks
  const int xcd = id & 7, slot = id >> 3;
  const int bh = xcd * 4 + (slot >> 4);  // 4 heads per XCD (K/V L2-resident)
  const int qt = slot & 15;              // 16 q-tiles of 128

  const int t = threadIdx.x, wave = t >> 6, lane = t & 63;
  const int kg = wave >> 2, w4 = wave & 3;
  const int g = lane >> 4, c = lane & 15;
  const int q0 = qt * 128 + w4 * 32;
  const H16* qp = q + ((size_t)bh * S + q0) * HW;
  const H16* kp = k + ((size_t)bh * S + kg * (S / 2)) * HW;
  const H16* vp = vt + (size_t)bh * HW * S + kg * (S / 2);

  // Q^T B-frags, 2 query groups, pre-scaled by 1/sqrt(64)*log2e
  const H16 scq = (H16)(0.125f * 1.44269504088896f);
  half8 qb[2][2];
#pragma unroll
  for (int qg = 0; qg < 2; ++qg) {
    qb[qg][0] = *(const half8*)&qp[(qg * 16 + c) * HW + g * 8];
    qb[qg][1] = *(const half8*)&qp[(qg * 16 + c) * HW + 32 + g * 8];
#pragma unroll
    for (int e = 0; e < 8; ++e) {
      qb[qg][0][e] *= scq;
      qb[qg][1][e] *= scq;
    }
  }

  // Direct per-lane fragment bases.
  // K A-frag for (kt,h): lane (c,g) reads K[key][h*32 + g*8 ..+7] with
  //   key = 32*(kt>>1) + 4*(kt&1) + 8*(c>>2) + (c&3)   (kperm from v13)
  // -> st[kt][qg][r] = score(key 32*(kt>>1)+8g+4*(kt&1)+r), so the owned
  //    P-values are exactly the PV B-frag elements (register-resident P).
  const H16* klane = kp + (size_t)(8 * (c >> 2) + (c & 3)) * HW + g * 8;
  // V A-frag for (wt,h): lane (c,g) reads V^T[wt*16+c][ck + h*32 + g*8 ..]
  const H16* vlane = vp + (size_t)c * S + g * 8;

  f32x4 o[4][2] = {};
  float l[2] = {0.f, 0.f};

  for (int it = 0; it < NIT; ++it) {
    const int kofs = it * 64 * HW;
    const int vofs = it * 64;

    // K fragments (8 x 16B, independent -> overlapping L2 loads)
    half8 kf[4][2];
#pragma unroll
    for (int kt = 0; kt < 4; ++kt) {
      const int ko = kofs + (32 * (kt >> 1) + 4 * (kt & 1)) * HW;
      kf[kt][0] = *(const half8*)(klane + ko);
      kf[kt][1] = *(const half8*)(klane + ko + 32);
    }

    // QK^T per kt, exp2 + pack immediately (keeps st footprint at 8 regs)
    half8 pb[2][2];
#pragma unroll
    for (int kt = 0; kt < 4; ++kt) {
      f32x4 st[2];
      __builtin_amdgcn_s_setprio(1);
#pragma unroll
      for (int qg = 0; qg < 2; ++qg) {
        f32x4 z = {};
        st[qg] = __builtin_amdgcn_mfma_f32_16x16x32_f16(kf[kt][0], qb[qg][0],
                                                        z, 0, 0, 0);
        st[qg] = __builtin_amdgcn_mfma_f32_16x16x32_f16(kf[kt][1], qb[qg][1],
                                                        st[qg], 0, 0, 0);
      }
      __builtin_amdgcn_s_setprio(0);
#pragma unroll
      for (int qg = 0; qg < 2; ++qg) {
        float p0 = __builtin_amdgcn_exp2f(st[qg][0]);
        float p1 = __builtin_amdgcn_exp2f(st[qg][1]);
        float p2 = __builtin_amdgcn_exp2f(st[qg][2]);
        float p3 = __builtin_amdgcn_exp2f(st[qg][3]);
        l[qg] += (p0 + p1) + (p2 + p3);
        pb[qg][kt >> 1][(kt & 1) * 4 + 0] = (H16)p0;
        pb[qg][kt >> 1][(kt & 1) * 4 + 1] = (H16)p1;
        pb[qg][kt >> 1][(kt & 1) * 4 + 2] = (H16)p2;
        pb[qg][kt >> 1][(kt & 1) * 4 + 3] = (H16)p3;
      }
    }

    // O^T += V^T · P (V frags direct from global, shared across qg)
#pragma unroll
    for (int wt = 0; wt < 4; ++wt) {
      half8 v0 = *(const half8*)(vlane + (size_t)wt * 16 * S + vofs);
      half8 v1 = *(const half8*)(vlane + (size_t)wt * 16 * S + vofs + 32);
      __builtin_amdgcn_s_setprio(1);
#pragma unroll
      for (int qg = 0; qg < 2; ++qg) {
        o[wt][qg] = __builtin_amdgcn_mfma_f32_16x16x32_f16(v0, pb[qg][0],
                                                           o[wt][qg], 0, 0, 0);
        o[wt][qg] = __builtin_amdgcn_mfma_f32_16x16x32_f16(v1, pb[qg][1],
                                                           o[wt][qg], 0, 0, 0);
      }
      __builtin_amdgcn_s_setprio(0);
    }
  }

  // wave-local l reduce across the 4 g-lane groups (lane bits 4,5)
#pragma unroll
  for (int qg = 0; qg < 2; ++qg) {
    l[qg] += __shfl_xor(l[qg], 16, 64);
    l[qg] += __shfl_xor(l[qg], 32, 64);
  }

  // cross-group combine: kg=1 dumps unnormalized O + l; kg=0 finishes.
  if (kg == 1) {
    float* dst = pex[w4];
#pragma unroll
    for (int wt = 0; wt < 4; ++wt)
#pragma unroll
      for (int qg = 0; qg < 2; ++qg)
        *(f32x4*)&dst[(wt * 2 + qg) * 256 + lane * 4] = o[wt][qg];
    if (g == 0) {
      lx[w4][0][c] = l[0];
      lx[w4][1][c] = l[1];
    }
  }
  __syncthreads();
  if (kg == 0) {
    const float* src = pex[w4];
    const int bbx = bh >> 4, h = bh & 15;
#pragma unroll
    for (int qg = 0; qg < 2; ++qg) {
      const float inv = 1.0f / (l[qg] + lx[w4][qg][c]);
      float* orow = out + ((size_t)bbx * S + q0 + qg * 16 + c) * D + h * HW;
#pragma unroll
      for (int wt = 0; wt < 4; ++wt) {
        f32x4 po = *(const f32x4*)&src[(wt * 2 + qg) * 256 + lane * 4];
        float4 v4 = {(o[wt][qg][0] + po[0]) * inv, (o[wt][qg][1] + po[1]) * inv,
                     (o[wt][qg][2] + po[2]) * inv, (o[wt][qg][3] + po[3]) * inv};
        *(float4*)&orow[wt * 16 + g * 4] = v4;
      }
    }
  }
}

extern "C" void kernel_launch(void* const* d_in, const int* in_sizes, int n_in,
                              void* d_out, int out_size, void* d_ws,
                              size_t ws_size, hipStream_t stream) {
  const float* x = (const float*)d_in[0];
  const float* Wq = (const float*)d_in[1];
  const float* bq = (const float*)d_in[2];
  const float* Wk = (const float*)d_in[3];
  const float* bk = (const float*)d_in[4];
  const float* Wv = (const float*)d_in[5];
  const float* bv = (const float*)d_in[6];
  float* out = (float*)d_out;
  char* ws = (char*)d_ws;
  H16* xh = (H16*)(ws + XH_OFF);
  H16* wt = (H16*)(ws + WT_OFF);
  H16* qw = (H16*)(ws + Q_OFF);
  H16* kw = (H16*)(ws + K_OFF);
  H16* vtw = (H16*)(ws + VT_OFF);

  prep<<<dim3(16, 16, 4), 256, 0, stream>>>(x, xh, Wq, Wk, Wv, wt);
  qkv_gemm<<<dim3(8, 32, 3), 256, 0, stream>>>(xh, wt, bq, bk, bv, qw, kw, vtw);
  attn<<<dim3(512), 512, 0, stream>>>(qw, kw, vtw, out);
}

// Round 7
// 166.361 us; speedup vs baseline: 1.4654x; 1.4654x over previous
//
#include <hip/hip_runtime.h>

typedef _Float16 H16;
typedef _Float16 half8 __attribute__((ext_vector_type(8)));
typedef _Float16 half4 __attribute__((ext_vector_type(4)));
typedef float f32x4 __attribute__((ext_vector_type(4)));

// problem dims
constexpr int Bb = 2, S = 2048, D = 1024, NH = 16, HW = 64;
constexpr int M = Bb * S;  // 4096

// workspace layout (bytes) — identical to the proven 166us version (38 MB)
constexpr size_t XH_OFF = 0;                               // [M][D] f16
constexpr size_t WT_OFF = XH_OFF + (size_t)M * D * 2;      // 3x [D(n)][D(k)] f16
constexpr size_t Q_OFF  = WT_OFF + 3ull * D * D * 2;       // [B][NH][S][HW] f16
constexpr size_t K_OFF  = Q_OFF + (size_t)M * D * 2;       // [B][NH][S][HW] f16
constexpr size_t VT_OFF = K_OFF + (size_t)M * D * 2;       // [B][NH][HW][S] f16

#define GLOAD_LDS16(g, l)                                        \
  __builtin_amdgcn_global_load_lds(                              \
      (const __attribute__((address_space(1))) void*)(g),        \
      (__attribute__((address_space(3))) void*)(l), 16, 0, 0)

// ---------------- fused prep: x fp32->fp16 (z=0) + W^T fp16 (z=1..3) --------
__global__ __launch_bounds__(256) void prep(const float* __restrict__ x,
                                            H16* __restrict__ xh,
                                            const float* __restrict__ w0,
                                            const float* __restrict__ w1,
                                            const float* __restrict__ w2,
                                            H16* __restrict__ wt) {
  __shared__ H16 tile[64][65];
  const int z = blockIdx.z;
  const int t = threadIdx.x;
  if (z == 0) {
    // 256 blocks, each converts 8 chunks of 2048 f16
    const int bid = blockIdx.y * 16 + blockIdx.x;
#pragma unroll
    for (int r = 0; r < 8; ++r) {
      size_t i = ((size_t)(bid * 8 + r) * 256 + t) * 8;
      float4 a = *(const float4*)(x + i);
      float4 b = *(const float4*)(x + i + 4);
      half8 h = {(H16)a.x, (H16)a.y, (H16)a.z, (H16)a.w,
                 (H16)b.x, (H16)b.y, (H16)b.z, (H16)b.w};
      *(half8*)(xh + i) = h;
    }
  } else {
    const float* w = z == 1 ? w0 : z == 2 ? w1 : w2;
    H16* out = wt + (size_t)(z - 1) * D * D;
    int c = t & 63, r4 = t >> 6;
    int bx = blockIdx.x * 64, by = blockIdx.y * 64;
#pragma unroll 4
    for (int it = 0; it < 16; ++it) {
      int row = it * 4 + r4;
      tile[c][row] = (H16)w[(size_t)(by + row) * D + bx + c];
    }
    __syncthreads();
#pragma unroll 4
    for (int it = 0; it < 16; ++it) {
      int row = it * 4 + r4;
      out[(size_t)(bx + row) * D + by + c] = tile[row][c];
    }
  }
}

// ---------------- fused QKV GEMM (fp16 MFMA, 128x128x64, swizzled) ----------
// Round-4 MEASURED version (48.2 us, 0 bank conflicts, FETCH 29.8MB):
// T2 XOR swizzle via pre-swizzled global source + XCD-aware remap.
// (r5 dbuf: refuted. r6: untouched. Kept verbatim.)
__global__ __launch_bounds__(256) void qkv_gemm(
    const H16* __restrict__ xh, const H16* __restrict__ wt,
    const float* __restrict__ bq, const float* __restrict__ bk,
    const float* __restrict__ bv, H16* __restrict__ qo, H16* __restrict__ ko,
    H16* __restrict__ vto) {
  __shared__ __align__(16) H16 As[128 * 64];
  __shared__ __align__(16) H16 Bs[128 * 64];
  const int lin = blockIdx.x + blockIdx.y * 8 + blockIdx.z * 256;
  const int wid = (lin & 7) * 96 + (lin >> 3);
  const int z = wid >> 8;
  const int rem = wid & 255;
  const int bm = (rem >> 3) * 128, bn = (rem & 7) * 128;
  const H16* w = wt + (size_t)z * D * D;
  const float* bias = z == 0 ? bq : z == 1 ? bk : bv;
  const int t = threadIdx.x;
  const int wave = t >> 6, lane = t & 63;
  const int g = lane >> 4, c = lane & 15;
  const int wm = (wave >> 1) * 64, wn = (wave & 1) * 64;

  // swizzled fragment read offsets (row&7 == c&7 since wm,i*16 are 16-mult)
  const int sw0 = (g ^ (c & 7)) * 8;
  const int sw1 = ((4 + g) ^ (c & 7)) * 8;

  f32x4 acc[4][4] = {};

  for (int kk = 0; kk < D; kk += 64) {
#pragma unroll
    for (int rnd = 0; rnd < 4; ++rnd) {
      int cid = rnd * 256 + t;
      int row = cid >> 3, j = cid & 7;
      int k0 = (j ^ (row & 7)) * 8;  // pre-swizzled global source
      GLOAD_LDS16(&xh[(size_t)(bm + row) * D + kk + k0], &As[cid * 8]);
      GLOAD_LDS16(&w[(size_t)(bn + row) * D + kk + k0], &Bs[cid * 8]);
    }
    __syncthreads();
#pragma unroll
    for (int kc = 0; kc < 2; ++kc) {
      const int ro = kc ? sw1 : sw0;
      half8 af[4], bf[4];
#pragma unroll
      for (int i = 0; i < 4; ++i) {
        af[i] = *(const half8*)&As[(wm + i * 16 + c) * 64 + ro];
        bf[i] = *(const half8*)&Bs[(wn + i * 16 + c) * 64 + ro];
      }
#pragma unroll
      for (int i = 0; i < 4; ++i)
#pragma unroll
        for (int j2 = 0; j2 < 4; ++j2)
          acc[i][j2] = __builtin_amdgcn_mfma_f32_16x16x32_f16(af[i], bf[j2],
                                                              acc[i][j2], 0, 0, 0);
    }
    __syncthreads();
  }

#pragma unroll
  for (int i = 0; i < 4; ++i) {
#pragma unroll
    for (int j = 0; j < 4; ++j) {
      int coln = bn + wn + j * 16 + c;
      float bse = bias[coln];
      int h = coln >> 6, wcol = coln & 63;
      if (z == 2) {
        int row0 = bm + wm + i * 16 + g * 4;
        int bbx = row0 >> 11, s0 = row0 & (S - 1);
        half4 v4 = {(H16)(acc[i][j][0] + bse), (H16)(acc[i][j][1] + bse),
                    (H16)(acc[i][j][2] + bse), (H16)(acc[i][j][3] + bse)};
        *(half4*)&vto[((size_t)(bbx * NH + h) * HW + wcol) * S + s0] = v4;
      } else {
#pragma unroll
        for (int r = 0; r < 4; ++r) {
          int row = bm + wm + i * 16 + g * 4 + r;
          float val = acc[i][j][r] + bse;
          int bbx = row >> 11, s = row & (S - 1);
          size_t bh = (size_t)(bbx * NH + h);
          if (z == 0)
            qo[(bh * S + s) * HW + wcol] = (H16)val;
          else
            ko[(bh * S + s) * HW + wcol] = (H16)val;
        }
      }
    }
  }
}

// ---------------- flash attention v15: v13 + hoisted fragment reads --------
// v13 (register-P via kperm, LDS dbuf staging, intra-block kg combine) —
// the best measured attn (r4, <=48us). r6's no-LDS variant refuted (L2
// channel-serialized strided loads). Change here: ALL 16 ds_read_b128
// (K frags AND V frags) issue at the top of the iteration, before QK^T.
// V reads have no dependence on P, so the compiler can overlap the DS
// burst with QK-MFMA + exp2 via counted lgkmcnt waits, breaking the
// barrier-induced phase alignment of the 8 waves (each pipe was burst-
// oversubscribed 4x while the others idled: Mfma 28 / VALU 35 / DS ~28,
// nothing saturated). No setprio (r5: neutral-to-negative).
// Cost: +32 VGPR (8 live half8), ~100 total, under the 128 cap.
__global__ __launch_bounds__(512, 4) void attn(const H16* __restrict__ q,
                                               const H16* __restrict__ k,
                                               const H16* __restrict__ vt,
                                               float* __restrict__ out) {
  constexpr int NIT = S / 128;  // 16 chunks of 64 keys per key-group
  __shared__ __align__(16) H16 Ks[2][2][64 * 64];  // [buf][kg]
  __shared__ __align__(16) H16 Vs[2][2][64 * 64];
  __shared__ float lx[4][2][16];

  const int id = blockIdx.x;  // 512 blocks
  const int xcd = id & 7, slot = id >> 3;
  const int bh = xcd * 4 + (slot >> 4);  // 4 heads per XCD
  const int qt = slot & 15;              // 16 q-tiles of 128

  const int t = threadIdx.x, wave = t >> 6, lane = t & 63;
  const int kg = wave >> 2, w4 = wave & 3;
  const int g = lane >> 4, c = lane & 15;
  const int q0 = qt * 128 + w4 * 32;
  const H16* qp = q + ((size_t)bh * S + q0) * HW;
  const H16* kp = k + ((size_t)bh * S + kg * (S / 2)) * HW;
  const H16* vp = vt + (size_t)bh * HW * S + kg * (S / 2);

  // staging: 256 threads per key-group; LDS linear unit u=tt (and tt+256):
  // row qpos=u>>3, 16B slot j=u&7. Slot j of row qpos holds data chunk
  // j^(qpos&7) (XOR swizzle via the global address). K row qpos holds key
  // kperm(qpos) = 32*(qpos>>5) + 8*((qpos>>2)&3) + 4*((qpos>>4)&1) + (qpos&3).
  const int tt = t & 255;
  const int sq = tt >> 3, sj = tt & 7;
  const int kkey = ((sq >> 2) & 3) * 8 + ((sq >> 4) & 1) * 4 + (sq & 3);
  const int scol = (sj ^ (sq & 7)) * 8;
  const H16* kga = kp + (size_t)kkey * HW + scol;         // unit tt
  const H16* kgb = kp + (size_t)(32 + kkey) * HW + scol;  // unit tt+256
  const H16* vga = vp + (size_t)sq * S + scol;
  const H16* vgb = vp + (size_t)(sq + 32) * S + scol;

#define STAGE(bufi, nck)                                                  \
  {                                                                       \
    GLOAD_LDS16(kga + (size_t)(nck) * HW, &Ks[bufi][kg][tt * 8]);         \
    GLOAD_LDS16(kgb + (size_t)(nck) * HW, &Ks[bufi][kg][2048 + tt * 8]);  \
    GLOAD_LDS16(vga + (nck), &Vs[bufi][kg][tt * 8]);                      \
    GLOAD_LDS16(vgb + (nck), &Vs[bufi][kg][2048 + tt * 8]);               \
  }

  // Q^T B-frags, 2 query groups, pre-scaled by 1/sqrt(64)*log2e
  const H16 scq = (H16)(0.125f * 1.44269504088896f);
  half8 qb[2][2];
#pragma unroll
  for (int qg = 0; qg < 2; ++qg) {
    qb[qg][0] = *(const half8*)&qp[(qg * 16 + c) * HW + g * 8];
    qb[qg][1] = *(const half8*)&qp[(qg * 16 + c) * HW + 32 + g * 8];
#pragma unroll
    for (int e = 0; e < 8; ++e) {
      qb[qg][0][e] *= scq;
      qb[qg][1][e] *= scq;
    }
  }

  f32x4 o[4][2] = {};
  float l[2] = {0.f, 0.f};

  // swizzled fragment read offsets (tile rows 16-aligned so row&7 == c&7)
  const int sw0 = (g ^ (c & 7)) * 8;
  const int sw1 = ((4 + g) ^ (c & 7)) * 8;

  STAGE(0, 0);
  int buf = 0;
  for (int it = 0; it < NIT; ++it) {
    __syncthreads();  // drains this wave's async loads; tile `it` ready
    if (it + 1 < NIT) STAGE(buf ^ 1, (it + 1) * 64);

    const H16* ks = Ks[buf][kg];
    const H16* vs = Vs[buf][kg];

    // issue ALL fragment reads up front: K then V (V has no dep on P, so
    // the whole DS burst overlaps QK-MFMA + exp2 via counted lgkm waits)
    half8 kf[4][2], vf[4][2];
#pragma unroll
    for (int kt = 0; kt < 4; ++kt) {
      const H16* kr = &ks[(kt * 16 + c) * 64];
      kf[kt][0] = *(const half8*)&kr[sw0];
      kf[kt][1] = *(const half8*)&kr[sw1];
    }
#pragma unroll
    for (int wt = 0; wt < 4; ++wt) {
      const H16* vr = &vs[(wt * 16 + c) * 64];
      vf[wt][0] = *(const half8*)&vr[sw0];
      vf[wt][1] = *(const half8*)&vr[sw1];
    }

    // S^T tiles: st[kt][qg], K frags shared across query groups.
    // st[kt][qg] reg r = score for key kperm(16kt+4g+r), query qg*16+c.
    f32x4 st[4][2];
#pragma unroll
    for (int kt = 0; kt < 4; ++kt) {
#pragma unroll
      for (int qg = 0; qg < 2; ++qg) {
        f32x4 z = {};
        st[kt][qg] =
            __builtin_amdgcn_mfma_f32_16x16x32_f16(kf[kt][0], qb[qg][0], z, 0, 0, 0);
        st[kt][qg] = __builtin_amdgcn_mfma_f32_16x16x32_f16(kf[kt][1], qb[qg][1],
                                                            st[kt][qg], 0, 0, 0);
      }
    }

    // p = exp2(raw); l partial; pack to f16 IN REGISTERS.
    // kperm makes lane (c,g) own keys {8g..8g+7} (st0,st1) and
    // {32+8g..32+8g+7} (st2,st3) -> pb0 = [st0,st1], pb1 = [st2,st3].
    half8 pb[2][2];
#pragma unroll
    for (int qg = 0; qg < 2; ++qg) {
#pragma unroll
      for (int kt = 0; kt < 4; ++kt) {
        float p0 = __builtin_amdgcn_exp2f(st[kt][qg][0]);
        float p1 = __builtin_amdgcn_exp2f(st[kt][qg][1]);
        float p2 = __builtin_amdgcn_exp2f(st[kt][qg][2]);
        float p3 = __builtin_amdgcn_exp2f(st[kt][qg][3]);
        l[qg] += (p0 + p1) + (p2 + p3);
        pb[qg][kt >> 1][(kt & 1) * 4 + 0] = (H16)p0;
        pb[qg][kt >> 1][(kt & 1) * 4 + 1] = (H16)p1;
        pb[qg][kt >> 1][(kt & 1) * 4 + 2] = (H16)p2;
        pb[qg][kt >> 1][(kt & 1) * 4 + 3] = (H16)p3;
      }
    }

    // O^T += V^T · P (V frags already in registers)
#pragma unroll
    for (int wt = 0; wt < 4; ++wt) {
#pragma unroll
      for (int qg = 0; qg < 2; ++qg) {
        o[wt][qg] = __builtin_amdgcn_mfma_f32_16x16x32_f16(vf[wt][0], pb[qg][0],
                                                           o[wt][qg], 0, 0, 0);
        o[wt][qg] = __builtin_amdgcn_mfma_f32_16x16x32_f16(vf[wt][1], pb[qg][1],
                                                           o[wt][qg], 0, 0, 0);
      }
    }
    buf ^= 1;
  }
#undef STAGE

  // wave-local l reduce across the 4 g-lane groups (lane bits 4,5)
#pragma unroll
  for (int qg = 0; qg < 2; ++qg) {
    l[qg] += __shfl_xor(l[qg], 16, 64);
    l[qg] += __shfl_xor(l[qg], 32, 64);
  }

  __syncthreads();  // all tile reads done -> K planes reusable as exchange

  // cross-group combine through the dead K tiles (32 KB = 4 x 8KB regions).
  float* pex = (float*)Ks;
  if (kg == 1) {
    float* dst = pex + w4 * 2048;
#pragma unroll
    for (int wt = 0; wt < 4; ++wt)
#pragma unroll
      for (int qg = 0; qg < 2; ++qg)
        *(f32x4*)&dst[(wt * 2 + qg) * 256 + lane * 4] = o[wt][qg];
    if (g == 0) {
      lx[w4][0][c] = l[0];
      lx[w4][1][c] = l[1];
    }
  }
  __syncthreads();
  if (kg == 0) {
    const float* src = pex + w4 * 2048;
    const int bbx = bh >> 4, h = bh & 15;
#pragma unroll
    for (int qg = 0; qg < 2; ++qg) {
      const float inv = 1.0f / (l[qg] + lx[w4][qg][c]);
      float* orow = out + ((size_t)bbx * S + q0 + qg * 16 + c) * D + h * HW;
#pragma unroll
      for (int wt = 0; wt < 4; ++wt) {
        f32x4 po = *(const f32x4*)&src[(wt * 2 + qg) * 256 + lane * 4];
        float4 v4 = {(o[wt][qg][0] + po[0]) * inv, (o[wt][qg][1] + po[1]) * inv,
                     (o[wt][qg][2] + po[2]) * inv, (o[wt][qg][3] + po[3]) * inv};
        *(float4*)&orow[wt * 16 + g * 4] = v4;
      }
    }
  }
}

extern "C" void kernel_launch(void* const* d_in, const int* in_sizes, int n_in,
                              void* d_out, int out_size, void* d_ws,
                              size_t ws_size, hipStream_t stream) {
  const float* x = (const float*)d_in[0];
  const float* Wq = (const float*)d_in[1];
  const float* bq = (const float*)d_in[2];
  const float* Wk = (const float*)d_in[3];
  const float* bk = (const float*)d_in[4];
  const float* Wv = (const float*)d_in[5];
  const float* bv = (const float*)d_in[6];
  float* out = (float*)d_out;
  char* ws = (char*)d_ws;
  H16* xh = (H16*)(ws + XH_OFF);
  H16* wt = (H16*)(ws + WT_OFF);
  H16* qw = (H16*)(ws + Q_OFF);
  H16* kw = (H16*)(ws + K_OFF);
  H16* vtw = (H16*)(ws + VT_OFF);

  prep<<<dim3(16, 16, 4), 256, 0, stream>>>(x, xh, Wq, Wk, Wv, wt);
  qkv_gemm<<<dim3(8, 32, 3), 256, 0, stream>>>(xh, wt, bq, bk, bv, qw, kw, vtw);
  attn<<<dim3(512), 512, 0, stream>>>(qw, kw, vtw, out);
}